// Round 4
// baseline (551.398 us; speedup 1.0000x reference)
//
#include <hip/hip_runtime.h>
#include <hip/hip_bf16.h>

// NodeProcessor via MFMA, register-built A-fragments (no LDS A round-trip).
// Per block: 64 edges, 4 waves. Each lane owns A-row e = wv*16+(lane&15) and
// builds its 8-elem A-frags from 1 LDS scalar x 8 hoisted registers.
//   GEMM-S: A_s[64e x 1280k] @ W_S[1280 x 96]  (bf16, B pre-packed in frag order)
//   GEMM-V: A_v[p][64e x 1280k] @ W_V[1280 x 32]
// mfma_f32_16x16x32_bf16; A: A[m=lane&15][k=quad*8+j]; B: n=lane&15,k=quad*8+j;
// C/D: col=lane&15, row=quad*4+reg.

#define NNODES 10000
#define NEDGES 160000

typedef unsigned short u16;
typedef unsigned int u32;
typedef short short8 __attribute__((ext_vector_type(8)));
typedef float f32x4 __attribute__((ext_vector_type(4)));

__device__ __forceinline__ float b2f(u16 u) {
  union { u32 i; float f; } v; v.i = ((u32)u) << 16; return v.f;
}
__device__ __forceinline__ u16 f2b(float f) {  // RNE
  union { float f; u32 i; } v; v.f = f;
  u32 r = v.i + 0x7FFFu + ((v.i >> 16) & 1u);
  return (u16)(r >> 16);
}
// pack two f32 -> dword of two truncated bf16 (lo in low half): 1 v_perm_b32
__device__ __forceinline__ u32 pk2(float lo, float hi) {
  return __builtin_amdgcn_perm(__float_as_uint(hi), __float_as_uint(lo), 0x07060302u);
}
union frag_u { u32 w[4]; short8 s; };

#define INVF  0.02795084971874737f   // 1/sqrt(1280)
#define INV3  0.5773502691896258f    // 1/sqrt(3)
#define INV2  0.7071067811865476f    // 1/sqrt(2)

// ---- pack weights into MFMA B-frag order, bf16, scales folded ------------
// WSp u16[6nt][40kt][64lane][8j]; WVp u16[2nt][40kt][64lane][8j]
__global__ void pack_kernel(const float* __restrict__ W_ss, const float* __restrict__ W_vv_s,
                            const float* __restrict__ W_sv, const float* __restrict__ W_vs,
                            const float* __restrict__ W_vv_v,
                            u32* __restrict__ WSd, u32* __restrict__ WVd) {
  int t = blockIdx.x * 256 + threadIdx.x;
  if (t < 61440) {            // W_S dwords
    int d = t;
    int nt = d / 10240, r = d - nt * 10240;
    int kt = r >> 8, l = (r & 255) >> 2, jp = r & 3;
    int n = nt * 16 + (l & 15);
    int k0 = kt * 32 + ((l >> 4) << 3) + jp * 2;
    float f0, f1;
    f0 = (k0     < 1024) ? W_ss[k0 * 96 + n] * INVF       : W_vv_s[(k0 - 1024) * 96 + n] * (INVF * INV3);
    f1 = (k0 + 1 < 1024) ? W_ss[(k0 + 1) * 96 + n] * INVF : W_vv_s[(k0 - 1023) * 96 + n] * (INVF * INV3);
    WSd[d] = (u32)f2b(f0) | ((u32)f2b(f1) << 16);
  } else if (t < 81920) {     // W_V dwords
    int d = t - 61440;
    int nt = d / 10240, r = d - nt * 10240;
    int kt = r >> 8, l = (r & 255) >> 2, jp = r & 3;
    int n = nt * 16 + (l & 15);
    int k0 = kt * 32 + ((l >> 4) << 3) + jp * 2;
    float f[2];
#pragma unroll
    for (int jj = 0; jj < 2; jj++) {
      int k = k0 + jj;
      if (k < 512)       f[jj] = W_sv[k * 32 + n] * INVF;
      else if (k < 1024) f[jj] = W_vs[(k - 512) * 32 + n] * INVF;
      else               f[jj] = W_vv_v[(k - 1024) * 32 + n] * (INVF * INV2);
    }
    WVd[d] = (u32)f2b(f[0]) | ((u32)f2b(f[1]) << 16);
  }
}

__global__ void zero_kernel(float* __restrict__ p, int n) {
  int t = blockIdx.x * 256 + threadIdx.x;
  if (t < n) p[t] = 0.f;
}

// ---- edge kernel ---------------------------------------------------------
__global__ __launch_bounds__(256, 3) void edge_kernel(
    const float* __restrict__ x, const float* __restrict__ ea,
    const int* __restrict__ eidx,
    const u16* __restrict__ WSp, const u16* __restrict__ WVp,
    float* __restrict__ s_n, float* __restrict__ v_n) {
  __shared__ int idxL[64];
  __shared__ u16 s1b[64][64];
  __shared__ u16 v1b[64][96];   // [e][a*3+p]
  __shared__ u16 s2b[64][16];
  __shared__ u16 v2b[64][24];   // [e][b*3+p]

  const int tid = threadIdx.x;
  const int eb = blockIdx.x * 64;
  if (tid < 64) idxL[tid] = eidx[eb + tid];
  __syncthreads();

  for (int t = tid; t < 64 * 160; t += 256) {
    int e = t / 160, j = t - e * 160;
    u16 v = f2b(x[(size_t)idxL[e] * 160 + j]);
    if (j < 64) s1b[e][j] = v; else v1b[e][j - 64] = v;
  }
  for (int t = tid; t < 64 * 40; t += 256) {
    int e = t / 40, j = t - e * 40;
    u16 v = f2b(ea[(eb + e) * 40 + j]);
    if (j < 16) s2b[e][j] = v; else v2b[e][j - 16] = v;
  }
  __syncthreads();

  const int wv = tid >> 6, lane = tid & 63;
  const int ln = lane & 15, quad = lane >> 4;
  const int e = wv * 16 + ln;            // this lane's A-row (edge)
  const int qh = quad >> 1, bb = (quad & 1) * 8;

  const u16* s1e = s1b[e];
  const u16* v1e = v1b[e];

  // hoist this edge's s2/v2 rows into registers
  float s2f[16], v2f[24];
#pragma unroll
  for (int i = 0; i < 16; i++) s2f[i] = b2f(s2b[e][i]);
#pragma unroll
  for (int i = 0; i < 24; i++) v2f[i] = b2f(v2b[e][i]);

  // ================= S phase =================
  f32x4 aS[6];
#pragma unroll
  for (int i = 0; i < 6; i++) aS[i] = (f32x4){0.f, 0.f, 0.f, 0.f};

  // region ss: kt 0..31, af[j] = s1[e][2kt+qh] * s2f[bb+j]
#pragma unroll 4
  for (int kt = 0; kt < 32; kt++) {
    float s1v = b2f(s1e[2 * kt + qh]);
    frag_u A;
#pragma unroll
    for (int jp = 0; jp < 4; jp++)
      A.w[jp] = pk2(s1v * s2f[bb + 2 * jp], s1v * s2f[bb + 2 * jp + 1]);
    const u16* Bb = WSp + (size_t)(kt * 64 + lane) * 8;
#pragma unroll
    for (int nt = 0; nt < 6; nt++) {
      short8 bf = *(const short8*)(Bb + nt * 20480);
      aS[nt] = __builtin_amdgcn_mfma_f32_16x16x32_bf16(A.s, bf, aS[nt], 0, 0, 0);
    }
  }
  // region dot3: kt 32..39, a = 4*kt2+quad, af[j] = dot3(v1[e][a], v2[e][j])
#pragma unroll 2
  for (int kt2 = 0; kt2 < 8; kt2++) {
    const u16* vp = v1e + (4 * kt2 + quad) * 3;
    float x0 = b2f(vp[0]), x1 = b2f(vp[1]), x2 = b2f(vp[2]);
    frag_u A;
#pragma unroll
    for (int jp = 0; jp < 4; jp++) {
      int j0 = 2 * jp, j1 = 2 * jp + 1;
      float d0 = x0 * v2f[j0 * 3] + x1 * v2f[j0 * 3 + 1] + x2 * v2f[j0 * 3 + 2];
      float d1 = x0 * v2f[j1 * 3] + x1 * v2f[j1 * 3 + 1] + x2 * v2f[j1 * 3 + 2];
      A.w[jp] = pk2(d0, d1);
    }
    const u16* Bb = WSp + (size_t)((kt2 + 32) * 64 + lane) * 8;
#pragma unroll
    for (int nt = 0; nt < 6; nt++) {
      short8 bf = *(const short8*)(Bb + nt * 20480);
      aS[nt] = __builtin_amdgcn_mfma_f32_16x16x32_bf16(A.s, bf, aS[nt], 0, 0, 0);
    }
  }

  // S epilogue: silu -> atomics; sigmoid gates -> registers
  float gateR[8];                        // [nt2*4 + r]
#pragma unroll
  for (int r = 0; r < 4; r++) {
    int er = wv * 16 + quad * 4 + r;
    int nid = idxL[er];
#pragma unroll
    for (int nt = 0; nt < 6; nt++) {
      float v = aS[nt][r];
      float sg = 1.f / (1.f + __expf(-v));
      if (nt < 4) atomicAdd(&s_n[nid * 64 + nt * 16 + ln], v * sg);
      else        gateR[(nt - 4) * 4 + r] = sg;
    }
  }

  // ================= V phase =================
  f32x4 aV[3][2];
#pragma unroll
  for (int p = 0; p < 3; p++)
#pragma unroll
    for (int nt = 0; nt < 2; nt++) aV[p][nt] = (f32x4){0.f, 0.f, 0.f, 0.f};

  // region sv: kt 0..15, af_p[j] = s1[e][4kt+quad] * v2f[j*3+p]
#pragma unroll 2
  for (int kt = 0; kt < 16; kt++) {
    float s1v = b2f(s1e[4 * kt + quad]);
    const u16* Bb = WVp + (size_t)(kt * 64 + lane) * 8;
    short8 bf0 = *(const short8*)(Bb);
    short8 bf1 = *(const short8*)(Bb + 20480);
#pragma unroll
    for (int p = 0; p < 3; p++) {
      frag_u A;
#pragma unroll
      for (int jp = 0; jp < 4; jp++)
        A.w[jp] = pk2(s1v * v2f[(2 * jp) * 3 + p], s1v * v2f[(2 * jp + 1) * 3 + p]);
      aV[p][0] = __builtin_amdgcn_mfma_f32_16x16x32_bf16(A.s, bf0, aV[p][0], 0, 0, 0);
      aV[p][1] = __builtin_amdgcn_mfma_f32_16x16x32_bf16(A.s, bf1, aV[p][1], 0, 0, 0);
    }
  }
  // region vs: kt 16..31, a = 2*kt2+qh, af_p[j] = v1[e][a*3+p] * s2f[bb+j]
#pragma unroll 2
  for (int kt2 = 0; kt2 < 16; kt2++) {
    const u16* vp = v1e + (2 * kt2 + qh) * 3;
    float w0 = b2f(vp[0]), w1 = b2f(vp[1]), w2 = b2f(vp[2]);
    const u16* Bb = WVp + (size_t)((kt2 + 16) * 64 + lane) * 8;
    short8 bf0 = *(const short8*)(Bb);
    short8 bf1 = *(const short8*)(Bb + 20480);
#pragma unroll
    for (int p = 0; p < 3; p++) {
      float vv = (p == 0) ? w0 : ((p == 1) ? w1 : w2);
      frag_u A;
#pragma unroll
      for (int jp = 0; jp < 4; jp++)
        A.w[jp] = pk2(vv * s2f[bb + 2 * jp], vv * s2f[bb + 2 * jp + 1]);
      aV[p][0] = __builtin_amdgcn_mfma_f32_16x16x32_bf16(A.s, bf0, aV[p][0], 0, 0, 0);
      aV[p][1] = __builtin_amdgcn_mfma_f32_16x16x32_bf16(A.s, bf1, aV[p][1], 0, 0, 0);
    }
  }
  // region cross: kt 32..39, a = 4*kt2+quad, af_p[j] = cross(v1[e][a], v2[e][j])[p]
#pragma unroll 2
  for (int kt2 = 0; kt2 < 8; kt2++) {
    const u16* vp = v1e + (4 * kt2 + quad) * 3;
    float w[3] = { b2f(vp[0]), b2f(vp[1]), b2f(vp[2]) };
    const u16* Bb = WVp + (size_t)((kt2 + 32) * 64 + lane) * 8;
    short8 bf0 = *(const short8*)(Bb);
    short8 bf1 = *(const short8*)(Bb + 20480);
#pragma unroll
    for (int p = 0; p < 3; p++) {
      const int p1 = (p + 1) % 3, p2 = (p + 2) % 3;
      frag_u A;
#pragma unroll
      for (int jp = 0; jp < 4; jp++) {
        int j0 = 2 * jp, j1 = 2 * jp + 1;
        float d0 = w[p1] * v2f[j0 * 3 + p2] - w[p2] * v2f[j0 * 3 + p1];
        float d1 = w[p1] * v2f[j1 * 3 + p2] - w[p2] * v2f[j1 * 3 + p1];
        A.w[jp] = pk2(d0, d1);
      }
      aV[p][0] = __builtin_amdgcn_mfma_f32_16x16x32_bf16(A.s, bf0, aV[p][0], 0, 0, 0);
      aV[p][1] = __builtin_amdgcn_mfma_f32_16x16x32_bf16(A.s, bf1, aV[p][1], 0, 0, 0);
    }
  }

  // V epilogue: gate + scatter
#pragma unroll
  for (int r = 0; r < 4; r++) {
    int er = wv * 16 + quad * 4 + r;
    int nid = idxL[er];
#pragma unroll
    for (int nt = 0; nt < 2; nt++) {
      int c = nt * 16 + ln;
      float g = gateR[nt * 4 + r];
#pragma unroll
      for (int p = 0; p < 3; p++)
        atomicAdd(&v_n[nid * 96 + c * 3 + p], aV[p][nt][r] * g);
    }
  }
}

// ---- BN stats ------------------------------------------------------------
__global__ void stats_kernel(const float* __restrict__ s_n, const float* __restrict__ v_n,
                             float* __restrict__ stats) {
  int b = blockIdx.x, tid = threadIdx.x;
  int r0 = b * 100;
  int c = tid & 63, rg = tid >> 6;
  float s = 0.f, sq = 0.f;
  for (int r = r0 + rg; r < r0 + 100; r += 4) {
    float v = s_n[r * 64 + c];
    s += v; sq += v * v;
  }
  atomicAdd(&stats[c], s);
  atomicAdd(&stats[64 + c], sq);
  int c2 = tid & 31, rg2 = tid >> 5;
  float vn = 0.f;
  for (int r = r0 + rg2; r < r0 + 100; r += 8) {
    const float* vp = &v_n[r * 96 + c2 * 3];
    vn += vp[0] * vp[0] + vp[1] * vp[1] + vp[2] * vp[2];
  }
  atomicAdd(&stats[128 + c2], vn);
}

// ---- finalize ------------------------------------------------------------
__global__ void finalize_kernel(const float* __restrict__ s_n, const float* __restrict__ v_n,
                                const float* __restrict__ stats,
                                const float* __restrict__ x,
                                const float* __restrict__ bw_s, const float* __restrict__ bb_s,
                                const float* __restrict__ bw_v,
                                float* __restrict__ out) {
  int t = blockIdx.x * 256 + threadIdx.x;
  if (t >= NNODES * 160) return;
  int n = t / 160, j = t - n * 160;
  float xv = x[t];
  float r;
  if (j < 64) {
    float mu  = stats[j] * (1.f / NNODES);
    float var = stats[64 + j] * (1.f / NNODES) - mu * mu;
    var = fmaxf(var, 0.f);
    float v = s_n[n * 64 + j];
    r = (v - mu) * rsqrtf(var + 1e-5f) * bw_s[j] + bb_s[j];
  } else {
    int qq = j - 64;
    int c = qq / 3;
    float vn = stats[128 + c] * (1.f / (3.f * NNODES));
    float v = v_n[n * 96 + qq];
    r = v * rsqrtf(vn + 1e-5f) * bw_v[c];
  }
  out[t] = r + xv;
}

extern "C" void kernel_launch(void* const* d_in, const int* in_sizes, int n_in,
                              void* d_out, int out_size, void* d_ws, size_t ws_size,
                              hipStream_t stream) {
  const float* x      = (const float*)d_in[0];
  const float* ea     = (const float*)d_in[1];
  const float* W_ss   = (const float*)d_in[2];
  const float* W_vv_s = (const float*)d_in[3];
  const float* W_sv   = (const float*)d_in[4];
  const float* W_vs   = (const float*)d_in[5];
  const float* W_vv_v = (const float*)d_in[6];
  const float* bw_s   = (const float*)d_in[7];
  const float* bb_s   = (const float*)d_in[8];
  const float* bw_v   = (const float*)d_in[9];
  const int* eidx     = (const int*)d_in[10];
  float* out = (float*)d_out;

  u16* WSp     = (u16*)d_ws;              // 122880 u16
  u16* WVp     = WSp + 122880;            // 40960 u16
  float* s_n   = (float*)d_ws + 81920;    // 640000
  float* v_n   = s_n + 640000;            // 960000
  float* stats = v_n + 960000;            // 160

  pack_kernel<<<320, 256, 0, stream>>>(W_ss, W_vv_s, W_sv, W_vs, W_vv_v,
                                       (u32*)WSp, (u32*)WVp);
  zero_kernel<<<(1600160 + 255) / 256, 256, 0, stream>>>(s_n, 1600160);
  edge_kernel<<<NEDGES / 64, 256, 0, stream>>>(x, ea, eidx, WSp, WVp, s_n, v_n);
  stats_kernel<<<100, 256, 0, stream>>>(s_n, v_n, stats);
  finalize_kernel<<<(NNODES * 160 + 255) / 256, 256, 0, stream>>>(
      s_n, v_n, stats, x, bw_s, bb_s, bw_v, out);
}

// Round 5
// 504.046 us; speedup vs baseline: 1.0939x; 1.0939x over previous
//
#include <hip/hip_runtime.h>
#include <hip/hip_bf16.h>

// NodeProcessor via MFMA, register-built A-fragments, TRANSPOSED LDS feature
// store fT[j][e] (stride 68 u16) -> all hot reads <=2-way bank aliasing.
// Edge work split into two kernels (S and V); V recomputes the gate tiles
// (B nt=4,5) from the same A-fragments instead of spilling gates to memory.
//   GEMM-S: A_s[64e x 1280k] @ W_S[1280 x 96]  (bf16, B pre-packed frag order)
//   GEMM-V: A_v[p][64e x 1280k] @ W_V[1280 x 32]
// mfma_f32_16x16x32_bf16; A: A[m=lane&15][k=quad*8+j]; B: n=lane&15,k=quad*8+j;
// C/D: col=lane&15, row=quad*4+reg.

#define NNODES 10000
#define NEDGES 160000

typedef unsigned short u16;
typedef unsigned int u32;
typedef short short8 __attribute__((ext_vector_type(8)));
typedef float f32x4 __attribute__((ext_vector_type(4)));

__device__ __forceinline__ float b2f(u16 u) {
  union { u32 i; float f; } v; v.i = ((u32)u) << 16; return v.f;
}
__device__ __forceinline__ u16 f2b(float f) {  // RNE
  union { float f; u32 i; } v; v.f = f;
  u32 r = v.i + 0x7FFFu + ((v.i >> 16) & 1u);
  return (u16)(r >> 16);
}
// pack two f32 -> dword of two truncated bf16 (lo in low half): 1 v_perm_b32
__device__ __forceinline__ u32 pk2(float lo, float hi) {
  return __builtin_amdgcn_perm(__float_as_uint(hi), __float_as_uint(lo), 0x07060302u);
}
union frag_u { u32 w[4]; short8 s; };

#define INVF  0.02795084971874737f   // 1/sqrt(1280)
#define INV3  0.5773502691896258f    // 1/sqrt(3)
#define INV2  0.7071067811865476f    // 1/sqrt(2)

#define FSTR 68                      // fT row stride in u16 (34 dwords, != 0 mod 32)

// ---- prep: pack weights into B-frag order + zero accumulators ------------
// WSp u16[6nt][40kt][64lane][8j]; WVp u16[2nt][40kt][64lane][8j]
__global__ void prep_kernel(const float* __restrict__ W_ss, const float* __restrict__ W_vv_s,
                            const float* __restrict__ W_sv, const float* __restrict__ W_vs,
                            const float* __restrict__ W_vv_v,
                            u32* __restrict__ WSd, u32* __restrict__ WVd,
                            float* __restrict__ zr) {
  int t = blockIdx.x * 256 + threadIdx.x;
  if (t < 1600160) zr[t] = 0.f;          // s_n + v_n + stats
  if (t < 61440) {            // W_S dwords
    int d = t;
    int nt = d / 10240, r = d - nt * 10240;
    int kt = r >> 8, l = (r & 255) >> 2, jp = r & 3;
    int n = nt * 16 + (l & 15);
    int k0 = kt * 32 + ((l >> 4) << 3) + jp * 2;
    float f0, f1;
    f0 = (k0     < 1024) ? W_ss[k0 * 96 + n] * INVF       : W_vv_s[(k0 - 1024) * 96 + n] * (INVF * INV3);
    f1 = (k0 + 1 < 1024) ? W_ss[(k0 + 1) * 96 + n] * INVF : W_vv_s[(k0 - 1023) * 96 + n] * (INVF * INV3);
    WSd[d] = (u32)f2b(f0) | ((u32)f2b(f1) << 16);
  } else if (t < 81920) {     // W_V dwords
    int d = t - 61440;
    int nt = d / 10240, r = d - nt * 10240;
    int kt = r >> 8, l = (r & 255) >> 2, jp = r & 3;
    int n = nt * 16 + (l & 15);
    int k0 = kt * 32 + ((l >> 4) << 3) + jp * 2;
    float f[2];
#pragma unroll
    for (int jj = 0; jj < 2; jj++) {
      int k = k0 + jj;
      if (k < 512)       f[jj] = W_sv[k * 32 + n] * INVF;
      else if (k < 1024) f[jj] = W_vs[(k - 512) * 32 + n] * INVF;
      else               f[jj] = W_vv_v[(k - 1024) * 32 + n] * (INVF * INV2);
    }
    WVd[d] = (u32)f2b(f[0]) | ((u32)f2b(f[1]) << 16);
  }
}

// ---- shared staging: fT[j][e] = feature j of edge e (bf16) ---------------
// j: 0..63 s1[a]; 64..159 v1[a*3+p]; 160..175 s2[b]; 176..199 v2[b*3+p]
__device__ __forceinline__ void stage_features(
    const float* __restrict__ x, const float* __restrict__ ea,
    const int* __restrict__ eidx, int eb, int tid,
    int* idxL, u16* fT) {
  if (tid < 64) idxL[tid] = eidx[eb + tid];
  __syncthreads();
  for (int t = tid; t < 64 * 200; t += 256) {
    int e = t / 200, j = t - e * 200;
    float v = (j < 160) ? x[(size_t)idxL[e] * 160 + j]
                        : ea[(size_t)(eb + e) * 40 + (j - 160)];
    fT[j * FSTR + e] = f2b(v);
  }
  __syncthreads();
}

// ---- S kernel: 4 output tiles (feat channels 0..63), silu + scatter ------
__global__ __launch_bounds__(256, 4) void edge_s_kernel(
    const float* __restrict__ x, const float* __restrict__ ea,
    const int* __restrict__ eidx, const u16* __restrict__ WSp,
    float* __restrict__ s_n) {
  __shared__ int idxL[64];
  __shared__ u16 fT[200 * FSTR];
  const int tid = threadIdx.x;
  stage_features(x, ea, eidx, blockIdx.x * 64, tid, idxL, fT);

  const int wv = tid >> 6, lane = tid & 63;
  const int ln = lane & 15, quad = lane >> 4;
  const int e = wv * 16 + ln;
  const int qh = quad >> 1, bb = (quad & 1) * 8;

  float s2h[8], v2f[24];
#pragma unroll
  for (int i = 0; i < 8; i++)  s2h[i] = b2f(fT[(160 + bb + i) * FSTR + e]);
#pragma unroll
  for (int i = 0; i < 24; i++) v2f[i] = b2f(fT[(176 + i) * FSTR + e]);

  f32x4 aS[4];
#pragma unroll
  for (int i = 0; i < 4; i++) aS[i] = (f32x4){0.f, 0.f, 0.f, 0.f};

  // region ss: kt 0..31, af[j] = s1[2kt+qh] * s2h[j]
#pragma unroll 4
  for (int kt = 0; kt < 32; kt++) {
    float s1v = b2f(fT[(2 * kt + qh) * FSTR + e]);
    frag_u A;
#pragma unroll
    for (int jp = 0; jp < 4; jp++)
      A.w[jp] = pk2(s1v * s2h[2 * jp], s1v * s2h[2 * jp + 1]);
    const u16* Bb = WSp + (size_t)(kt * 64 + lane) * 8;
#pragma unroll
    for (int nt = 0; nt < 4; nt++) {
      short8 bf = *(const short8*)(Bb + nt * 20480);
      aS[nt] = __builtin_amdgcn_mfma_f32_16x16x32_bf16(A.s, bf, aS[nt], 0, 0, 0);
    }
  }
  // region dot3: kt2 0..7, a = 4kt2+quad
#pragma unroll 2
  for (int kt2 = 0; kt2 < 8; kt2++) {
    int base = (64 + (4 * kt2 + quad) * 3) * FSTR + e;
    float x0 = b2f(fT[base]), x1 = b2f(fT[base + FSTR]), x2 = b2f(fT[base + 2 * FSTR]);
    frag_u A;
#pragma unroll
    for (int jp = 0; jp < 4; jp++) {
      int j0 = 2 * jp, j1 = 2 * jp + 1;
      float d0 = x0 * v2f[j0 * 3] + x1 * v2f[j0 * 3 + 1] + x2 * v2f[j0 * 3 + 2];
      float d1 = x0 * v2f[j1 * 3] + x1 * v2f[j1 * 3 + 1] + x2 * v2f[j1 * 3 + 2];
      A.w[jp] = pk2(d0, d1);
    }
    const u16* Bb = WSp + (size_t)((32 + kt2) * 64 + lane) * 8;
#pragma unroll
    for (int nt = 0; nt < 4; nt++) {
      short8 bf = *(const short8*)(Bb + nt * 20480);
      aS[nt] = __builtin_amdgcn_mfma_f32_16x16x32_bf16(A.s, bf, aS[nt], 0, 0, 0);
    }
  }

  // epilogue: silu -> atomics
#pragma unroll
  for (int r = 0; r < 4; r++) {
    int er = wv * 16 + quad * 4 + r;
    int nid = idxL[er];
#pragma unroll
    for (int nt = 0; nt < 4; nt++) {
      float v = aS[nt][r];
      float sg = 1.f / (1.f + __expf(-v));
      atomicAdd(&s_n[nid * 64 + nt * 16 + ln], v * sg);
    }
  }
}

// ---- V kernel: recompute gate tiles (nt=4,5 of W_S), then V GEMM ---------
__global__ __launch_bounds__(256, 3) void edge_v_kernel(
    const float* __restrict__ x, const float* __restrict__ ea,
    const int* __restrict__ eidx,
    const u16* __restrict__ WSp, const u16* __restrict__ WVp,
    float* __restrict__ v_n) {
  __shared__ int idxL[64];
  __shared__ u16 fT[200 * FSTR];
  const int tid = threadIdx.x;
  stage_features(x, ea, eidx, blockIdx.x * 64, tid, idxL, fT);

  const int wv = tid >> 6, lane = tid & 63;
  const int ln = lane & 15, quad = lane >> 4;
  const int e = wv * 16 + ln;
  const int qh = quad >> 1, bb = (quad & 1) * 8;

  float s2h[8], v2f[24];
#pragma unroll
  for (int i = 0; i < 8; i++)  s2h[i] = b2f(fT[(160 + bb + i) * FSTR + e]);
#pragma unroll
  for (int i = 0; i < 24; i++) v2f[i] = b2f(fT[(176 + i) * FSTR + e]);

  // ---- gate phase: S-GEMM tiles nt=4,5 ----
  f32x4 aG[2];
  aG[0] = (f32x4){0.f, 0.f, 0.f, 0.f};
  aG[1] = (f32x4){0.f, 0.f, 0.f, 0.f};
#pragma unroll 4
  for (int kt = 0; kt < 32; kt++) {
    float s1v = b2f(fT[(2 * kt + qh) * FSTR + e]);
    frag_u A;
#pragma unroll
    for (int jp = 0; jp < 4; jp++)
      A.w[jp] = pk2(s1v * s2h[2 * jp], s1v * s2h[2 * jp + 1]);
    const u16* Bb = WSp + (size_t)(kt * 64 + lane) * 8 + 4 * 20480;
#pragma unroll
    for (int g = 0; g < 2; g++) {
      short8 bf = *(const short8*)(Bb + g * 20480);
      aG[g] = __builtin_amdgcn_mfma_f32_16x16x32_bf16(A.s, bf, aG[g], 0, 0, 0);
    }
  }
#pragma unroll 2
  for (int kt2 = 0; kt2 < 8; kt2++) {
    int base = (64 + (4 * kt2 + quad) * 3) * FSTR + e;
    float x0 = b2f(fT[base]), x1 = b2f(fT[base + FSTR]), x2 = b2f(fT[base + 2 * FSTR]);
    frag_u A;
#pragma unroll
    for (int jp = 0; jp < 4; jp++) {
      int j0 = 2 * jp, j1 = 2 * jp + 1;
      float d0 = x0 * v2f[j0 * 3] + x1 * v2f[j0 * 3 + 1] + x2 * v2f[j0 * 3 + 2];
      float d1 = x0 * v2f[j1 * 3] + x1 * v2f[j1 * 3 + 1] + x2 * v2f[j1 * 3 + 2];
      A.w[jp] = pk2(d0, d1);
    }
    const u16* Bb = WSp + (size_t)((32 + kt2) * 64 + lane) * 8 + 4 * 20480;
#pragma unroll
    for (int g = 0; g < 2; g++) {
      short8 bf = *(const short8*)(Bb + g * 20480);
      aG[g] = __builtin_amdgcn_mfma_f32_16x16x32_bf16(A.s, bf, aG[g], 0, 0, 0);
    }
  }
  float gateR[8];
#pragma unroll
  for (int g = 0; g < 2; g++)
#pragma unroll
    for (int r = 0; r < 4; r++)
      gateR[g * 4 + r] = 1.f / (1.f + __expf(-aG[g][r]));

  // ---- V phase ----
  f32x4 aV[3][2];
#pragma unroll
  for (int p = 0; p < 3; p++)
#pragma unroll
    for (int nt = 0; nt < 2; nt++) aV[p][nt] = (f32x4){0.f, 0.f, 0.f, 0.f};

  // region sv: kt 0..15, af_p[j] = s1[4kt+quad] * v2f[j*3+p]
#pragma unroll 2
  for (int kt = 0; kt < 16; kt++) {
    float s1v = b2f(fT[(4 * kt + quad) * FSTR + e]);
    const u16* Bb = WVp + (size_t)(kt * 64 + lane) * 8;
    short8 bf0 = *(const short8*)(Bb);
    short8 bf1 = *(const short8*)(Bb + 20480);
#pragma unroll
    for (int p = 0; p < 3; p++) {
      frag_u A;
#pragma unroll
      for (int jp = 0; jp < 4; jp++)
        A.w[jp] = pk2(s1v * v2f[(2 * jp) * 3 + p], s1v * v2f[(2 * jp + 1) * 3 + p]);
      aV[p][0] = __builtin_amdgcn_mfma_f32_16x16x32_bf16(A.s, bf0, aV[p][0], 0, 0, 0);
      aV[p][1] = __builtin_amdgcn_mfma_f32_16x16x32_bf16(A.s, bf1, aV[p][1], 0, 0, 0);
    }
  }
  // region vs: kt2 0..15, a = 2kt2+qh, af_p[j] = v1[a*3+p] * s2h[j]
#pragma unroll 2
  for (int kt2 = 0; kt2 < 16; kt2++) {
    int base = (64 + (2 * kt2 + qh) * 3) * FSTR + e;
    float w0 = b2f(fT[base]), w1 = b2f(fT[base + FSTR]), w2 = b2f(fT[base + 2 * FSTR]);
    const u16* Bb = WVp + (size_t)((16 + kt2) * 64 + lane) * 8;
    short8 bf0 = *(const short8*)(Bb);
    short8 bf1 = *(const short8*)(Bb + 20480);
#pragma unroll
    for (int p = 0; p < 3; p++) {
      float vv = (p == 0) ? w0 : ((p == 1) ? w1 : w2);
      frag_u A;
#pragma unroll
      for (int jp = 0; jp < 4; jp++)
        A.w[jp] = pk2(vv * s2h[2 * jp], vv * s2h[2 * jp + 1]);
      aV[p][0] = __builtin_amdgcn_mfma_f32_16x16x32_bf16(A.s, bf0, aV[p][0], 0, 0, 0);
      aV[p][1] = __builtin_amdgcn_mfma_f32_16x16x32_bf16(A.s, bf1, aV[p][1], 0, 0, 0);
    }
  }
  // region cross: kt2 0..7, a = 4kt2+quad
#pragma unroll 2
  for (int kt2 = 0; kt2 < 8; kt2++) {
    int base = (64 + (4 * kt2 + quad) * 3) * FSTR + e;
    float w[3] = { b2f(fT[base]), b2f(fT[base + FSTR]), b2f(fT[base + 2 * FSTR]) };
    const u16* Bb = WVp + (size_t)((32 + kt2) * 64 + lane) * 8;
    short8 bf0 = *(const short8*)(Bb);
    short8 bf1 = *(const short8*)(Bb + 20480);
#pragma unroll
    for (int p = 0; p < 3; p++) {
      const int p1 = (p + 1) % 3, p2 = (p + 2) % 3;
      frag_u A;
#pragma unroll
      for (int jp = 0; jp < 4; jp++) {
        int j0 = 2 * jp, j1 = 2 * jp + 1;
        float d0 = w[p1] * v2f[j0 * 3 + p2] - w[p2] * v2f[j0 * 3 + p1];
        float d1 = w[p1] * v2f[j1 * 3 + p2] - w[p2] * v2f[j1 * 3 + p1];
        A.w[jp] = pk2(d0, d1);
      }
      aV[p][0] = __builtin_amdgcn_mfma_f32_16x16x32_bf16(A.s, bf0, aV[p][0], 0, 0, 0);
      aV[p][1] = __builtin_amdgcn_mfma_f32_16x16x32_bf16(A.s, bf1, aV[p][1], 0, 0, 0);
    }
  }

  // epilogue: gate + scatter
#pragma unroll
  for (int r = 0; r < 4; r++) {
    int er = wv * 16 + quad * 4 + r;
    int nid = idxL[er];
#pragma unroll
    for (int nt = 0; nt < 2; nt++) {
      int c = nt * 16 + ln;
      float g = gateR[nt * 4 + r];
#pragma unroll
      for (int p = 0; p < 3; p++)
        atomicAdd(&v_n[nid * 96 + c * 3 + p], aV[p][nt][r] * g);
    }
  }
}

// ---- BN stats ------------------------------------------------------------
__global__ void stats_kernel(const float* __restrict__ s_n, const float* __restrict__ v_n,
                             float* __restrict__ stats) {
  int b = blockIdx.x, tid = threadIdx.x;
  int r0 = b * 50;
  int c = tid & 63, rg = tid >> 6;
  float s = 0.f, sq = 0.f;
  for (int r = r0 + rg; r < r0 + 50; r += 4) {
    float v = s_n[r * 64 + c];
    s += v; sq += v * v;
  }
  atomicAdd(&stats[c], s);
  atomicAdd(&stats[64 + c], sq);
  int c2 = tid & 31, rg2 = tid >> 5;
  float vn = 0.f;
  for (int r = r0 + rg2; r < r0 + 50; r += 8) {
    const float* vp = &v_n[r * 96 + c2 * 3];
    vn += vp[0] * vp[0] + vp[1] * vp[1] + vp[2] * vp[2];
  }
  atomicAdd(&stats[128 + c2], vn);
}

// ---- finalize ------------------------------------------------------------
__global__ void finalize_kernel(const float* __restrict__ s_n, const float* __restrict__ v_n,
                                const float* __restrict__ stats,
                                const float* __restrict__ x,
                                const float* __restrict__ bw_s, const float* __restrict__ bb_s,
                                const float* __restrict__ bw_v,
                                float* __restrict__ out) {
  int t = blockIdx.x * 256 + threadIdx.x;
  if (t >= NNODES * 160) return;
  int n = t / 160, j = t - n * 160;
  float xv = x[t];
  float r;
  if (j < 64) {
    float mu  = stats[j] * (1.f / NNODES);
    float var = stats[64 + j] * (1.f / NNODES) - mu * mu;
    var = fmaxf(var, 0.f);
    float v = s_n[n * 64 + j];
    r = (v - mu) * rsqrtf(var + 1e-5f) * bw_s[j] + bb_s[j];
  } else {
    int qq = j - 64;
    int c = qq / 3;
    float vn = stats[128 + c] * (1.f / (3.f * NNODES));
    float v = v_n[n * 96 + qq];
    r = v * rsqrtf(vn + 1e-5f) * bw_v[c];
  }
  out[t] = r + xv;
}

extern "C" void kernel_launch(void* const* d_in, const int* in_sizes, int n_in,
                              void* d_out, int out_size, void* d_ws, size_t ws_size,
                              hipStream_t stream) {
  const float* x      = (const float*)d_in[0];
  const float* ea     = (const float*)d_in[1];
  const float* W_ss   = (const float*)d_in[2];
  const float* W_vv_s = (const float*)d_in[3];
  const float* W_sv   = (const float*)d_in[4];
  const float* W_vs   = (const float*)d_in[5];
  const float* W_vv_v = (const float*)d_in[6];
  const float* bw_s   = (const float*)d_in[7];
  const float* bb_s   = (const float*)d_in[8];
  const float* bw_v   = (const float*)d_in[9];
  const int* eidx     = (const int*)d_in[10];
  float* out = (float*)d_out;

  u16* WSp     = (u16*)d_ws;              // 122880 u16
  u16* WVp     = WSp + 122880;            // 40960 u16
  float* s_n   = (float*)d_ws + 81920;    // 640000
  float* v_n   = s_n + 640000;            // 960000
  float* stats = v_n + 960000;            // 160

  prep_kernel<<<6251, 256, 0, stream>>>(W_ss, W_vv_s, W_sv, W_vs, W_vv_v,
                                        (u32*)WSp, (u32*)WVp, s_n);
  edge_s_kernel<<<NEDGES / 64, 256, 0, stream>>>(x, ea, eidx, WSp, s_n);
  edge_v_kernel<<<NEDGES / 64, 256, 0, stream>>>(x, ea, eidx, WSp, WVp, v_n);
  stats_kernel<<<200, 256, 0, stream>>>(s_n, v_n, stats);
  finalize_kernel<<<(NNODES * 160 + 255) / 256, 256, 0, stream>>>(
      s_n, v_n, stats, x, bw_s, bb_s, bw_v, out);
}